// Round 10
// baseline (325.121 us; speedup 1.0000x reference)
//
#include <hip/hip_runtime.h>
#include <hip/hip_bf16.h>
#include <stdint.h>

#define M_DIM 8192
#define N_DIM 4096   // OUT_F
#define K_DIM 4096   // IN_F

#define BM 256
#define BN 256
#define BK 32
#define NT (K_DIM / BK)   // 128 K-tiles
#define NBUF 4

typedef __bf16 bf16_t;
typedef __attribute__((ext_vector_type(8))) __bf16 bf16x8;
typedef __attribute__((ext_vector_type(4))) float f32x4;

// ---------------- fp32 -> bf16 convert (vectorized, grid-stride) ----------------
__global__ void cvt_f32_to_bf16(const float* __restrict__ in, bf16_t* __restrict__ out, int n8) {
    int stride = gridDim.x * blockDim.x;
    for (int i = blockIdx.x * blockDim.x + threadIdx.x; i < n8; i += stride) {
        const float4* p = reinterpret_cast<const float4*>(in) + 2 * (size_t)i;
        float4 v0 = p[0];
        float4 v1 = p[1];
        bf16x8 o;
        o[0] = (bf16_t)v0.x; o[1] = (bf16_t)v0.y; o[2] = (bf16_t)v0.z; o[3] = (bf16_t)v0.w;
        o[4] = (bf16_t)v1.x; o[5] = (bf16_t)v1.y; o[6] = (bf16_t)v1.z; o[7] = (bf16_t)v1.w;
        *(reinterpret_cast<bf16x8*>(out) + (size_t)i) = o;
    }
}

// ---------------- 256x256 bf16 GEMM: r5 structure + T19 MFMA/DS interleave ----------------
// A: [M][K] bf16 row-major; B: [N][K] bf16 row-major (weight = B^T layout);
// C = A*B^T + bias, fp32 out.
//
// Structure identical to r5 (best: 247 us, MfmaUtil 50, 0 conflicts, passed):
// 4-deep ring; per tile: stage(T+3); 4 ds_read (x4-7); cluster-1 16 MFMA
// (carried); vmcnt(8); MID bar; 8 RA ds_reads (T+1 cluster-1 operands);
// cluster-2 16 MFMA; END bar. Hazard proofs unchanged from r5.
//
// NEW: sched_group_barrier forces per-instruction MFMA<->ds_read interleave.
// Mechanism: wave issue is in-order; a clustered 16-MFMA run blocks the
// wave's issue on matrix-pipe backpressure, so its following ds_reads can't
// issue, and (barrier-synced) no other wave feeds the LDS pipe either ->
// LDS and MFMA times SUM (observed 2320 cyc/tile = 1156 LDS + 1032 MFMA).
// Interleaving in program order feeds both pipes from one wave's stream.
// All interleaved MFMAs use carried regs (zero lgkm waits by construction);
// all reads feed future clusters (no WAR: RA writes opposite-parity regs).

#define MF(a, b, c) __builtin_amdgcn_mfma_f32_16x16x32_bf16((a), (b), (c), 0, 0, 0)
#define LD8(p) (*reinterpret_cast<const bf16x8*>(p))

#define SGB(m, n) __builtin_amdgcn_sched_group_barrier((m), (n), 0)
// segment 1: 4 ds_read + 16 MFMA -> 4x {1 DS_READ, 4 MFMA}
#define SGB_SEG1() { SGB(0x100,1); SGB(0x8,4); SGB(0x100,1); SGB(0x8,4);              \
                     SGB(0x100,1); SGB(0x8,4); SGB(0x100,1); SGB(0x8,4); }
// segment 2: 8 ds_read + 16 MFMA -> 8x {1 DS_READ, 2 MFMA}
#define SGB_SEG2() { SGB(0x100,1); SGB(0x8,2); SGB(0x100,1); SGB(0x8,2);              \
                     SGB(0x100,1); SGB(0x8,2); SGB(0x100,1); SGB(0x8,2);              \
                     SGB(0x100,1); SGB(0x8,2); SGB(0x100,1); SGB(0x8,2);              \
                     SGB(0x100,1); SGB(0x8,2); SGB(0x100,1); SGB(0x8,2); }

#define STAGE_A(T) {                                                                  \
    const int sb_ = (T) & 3; const size_t kof_ = (size_t)(T) * BK;                    \
    __builtin_amdgcn_global_load_lds(                                                 \
        (const __attribute__((address_space(1))) void*)(gA0 + kof_),                  \
        (__attribute__((address_space(3))) void*)(&Asm[sb_][dst0]), 16, 0, 0);        \
    __builtin_amdgcn_global_load_lds(                                                 \
        (const __attribute__((address_space(1))) void*)(gA1 + kof_),                  \
        (__attribute__((address_space(3))) void*)(&Asm[sb_][dst1]), 16, 0, 0);        \
}

#define STAGE_B(T) {                                                                  \
    const int sb_ = (T) & 3; const size_t kof_ = (size_t)(T) * BK;                    \
    __builtin_amdgcn_global_load_lds(                                                 \
        (const __attribute__((address_space(1))) void*)(gB0 + kof_),                  \
        (__attribute__((address_space(3))) void*)(&Bsm[sb_][dst0]), 16, 0, 0);        \
    __builtin_amdgcn_global_load_lds(                                                 \
        (const __attribute__((address_space(1))) void*)(gB1 + kof_),                  \
        (__attribute__((address_space(3))) void*)(&Bsm[sb_][dst1]), 16, 0, 0);        \
}

#define TILE(T, AC0,AC1,AC2,AC3, BC0,BC1,BC2,BC3,                                     \
             AN0,AN1,AN2,AN3, BN0,BN1,BN2,BN3, STG, VMSTR, RA)                        \
do {                                                                                  \
    bf16_t* Al_ = &Asm[(T) & 3][0];                                                   \
    bf16_t* An_ = &Asm[((T) + 1) & 3][0];                                             \
    bf16_t* Bn_ = &Bsm[((T) + 1) & 3][0];                                             \
    if (STG) STAGE_A((T) + 3);                                                        \
    /* cluster-2 A frags: consumed only in segment 2 */                               \
    bf16x8 x4_ = LD8(Al_ + oa4), x5_ = LD8(Al_ + oa5);                                \
    bf16x8 x6_ = LD8(Al_ + oa6), x7_ = LD8(Al_ + oa7);                                \
    if (STG) STAGE_B((T) + 3);                                                        \
    /* cluster 1: all operands carried -> no lgkm stall; interleaved with reads */    \
    acc[0][0]=MF(AC0,BC0,acc[0][0]); acc[0][1]=MF(AC0,BC1,acc[0][1]);                 \
    acc[0][2]=MF(AC0,BC2,acc[0][2]); acc[0][3]=MF(AC0,BC3,acc[0][3]);                 \
    acc[1][0]=MF(AC1,BC0,acc[1][0]); acc[1][1]=MF(AC1,BC1,acc[1][1]);                 \
    acc[1][2]=MF(AC1,BC2,acc[1][2]); acc[1][3]=MF(AC1,BC3,acc[1][3]);                 \
    acc[2][0]=MF(AC2,BC0,acc[2][0]); acc[2][1]=MF(AC2,BC1,acc[2][1]);                 \
    acc[2][2]=MF(AC2,BC2,acc[2][2]); acc[2][3]=MF(AC2,BC3,acc[2][3]);                 \
    acc[3][0]=MF(AC3,BC0,acc[3][0]); acc[3][1]=MF(AC3,BC1,acc[3][1]);                 \
    acc[3][2]=MF(AC3,BC2,acc[3][2]); acc[3][3]=MF(AC3,BC3,acc[3][3]);                 \
    SGB_SEG1();                                                                       \
    asm volatile(VMSTR ::: "memory");                                                 \
    __builtin_amdgcn_s_barrier();   /* MID: buf[T+1] staged data now visible */       \
    if (RA) {                                                                         \
        AN0 = LD8(An_ + oa0); AN1 = LD8(An_ + oa1);                                   \
        AN2 = LD8(An_ + oa2); AN3 = LD8(An_ + oa3);                                   \
        BN0 = LD8(Bn_ + ob0); BN1 = LD8(Bn_ + ob1);                                   \
        BN2 = LD8(Bn_ + ob2); BN3 = LD8(Bn_ + ob3);                                   \
    }                                                                                 \
    /* cluster 2: x4-7 read in segment 1 -> completed; interleaved with RA reads */   \
    acc[4][0]=MF(x4_,BC0,acc[4][0]); acc[4][1]=MF(x4_,BC1,acc[4][1]);                 \
    acc[4][2]=MF(x4_,BC2,acc[4][2]); acc[4][3]=MF(x4_,BC3,acc[4][3]);                 \
    acc[5][0]=MF(x5_,BC0,acc[5][0]); acc[5][1]=MF(x5_,BC1,acc[5][1]);                 \
    acc[5][2]=MF(x5_,BC2,acc[5][2]); acc[5][3]=MF(x5_,BC3,acc[5][3]);                 \
    acc[6][0]=MF(x6_,BC0,acc[6][0]); acc[6][1]=MF(x6_,BC1,acc[6][1]);                 \
    acc[6][2]=MF(x6_,BC2,acc[6][2]); acc[6][3]=MF(x6_,BC3,acc[6][3]);                 \
    acc[7][0]=MF(x7_,BC0,acc[7][0]); acc[7][1]=MF(x7_,BC1,acc[7][1]);                 \
    acc[7][2]=MF(x7_,BC2,acc[7][2]); acc[7][3]=MF(x7_,BC3,acc[7][3]);                 \
    if (RA) SGB_SEG2();                                                               \
    __builtin_amdgcn_s_barrier();   /* END: WAR fence for next STAGE */               \
} while (0)

__global__ __launch_bounds__(512, 2) void gemm_bf16_sgb(
        const bf16_t* __restrict__ A, const bf16_t* __restrict__ B,
        const float* __restrict__ bias, float* __restrict__ C) {

    __shared__ __align__(16) bf16_t Asm[NBUF][BM * BK];   // 4 x 16 KB
    __shared__ __align__(16) bf16_t Bsm[NBUF][BN * BK];   // 4 x 16 KB -> 128 KiB

    const int tid  = threadIdx.x;
    const int lane = tid & 63;
    const int wave = tid >> 6;        // 0..7
    const int wm   = wave >> 2;       // 0..1 : M half (128 rows)
    const int wn   = wave & 3;        // 0..3 : N quarter (64 cols)

    // XCD-aware swizzle (nwg = 512, divisible by 8 -> bijective)
    const int nwg = gridDim.x;
    const int cpx = nwg >> 3;
    const int swz = (blockIdx.x & 7) * cpx + (blockIdx.x >> 3);
    const int ntn = N_DIM / BN;       // 16
    const int brow = (swz / ntn) * BM;
    const int bcol = (swz % ntn) * BN;

    // ---- staging geometry (r2-proven): tile = 256 rows x 32 bf16 = 16KB =
    // 1024 x 16B slots; slot s holds (row = s>>2, chunk = (s&3)^((s>>3)&3)).
    const int slot0 = wave * 128 + lane;
    const int slot1 = slot0 + 64;
    const int r0 = slot0 >> 2, c0 = ((slot0 & 3) ^ ((slot0 >> 3) & 3)) << 3;
    const int r1 = slot1 >> 2, c1 = ((slot1 & 3) ^ ((slot1 >> 3) & 3)) << 3;
    const bf16_t* gA0 = A + (size_t)(brow + r0) * K_DIM + c0;
    const bf16_t* gA1 = A + (size_t)(brow + r1) * K_DIM + c1;
    const bf16_t* gB0 = B + (size_t)(bcol + r0) * K_DIM + c0;
    const bf16_t* gB1 = B + (size_t)(bcol + r1) * K_DIM + c1;
    const int dst0 = wave * 1024;     // elem offset (slot * 8)
    const int dst1 = dst0 + 512;

    // ---- ds_read fragment offsets (r2-proven, measured 0 bank conflicts)
    const int fr = lane & 15;
    const int cc = lane >> 4;         // k-chunk 0..3 (k = cc*8)
#define AOFF(p, mi) ({ int row_ = wm*128 + (p)*64 + (mi)*16 + fr; \
                       row_*32 + ((cc ^ ((row_ >> 1) & 3)) << 3); })
#define BOFF(ni)    ({ int row_ = wn*64 + (ni)*16 + fr; \
                       row_*32 + ((cc ^ ((row_ >> 1) & 3)) << 3); })
    const int oa0 = AOFF(0,0), oa1 = AOFF(0,1), oa2 = AOFF(0,2), oa3 = AOFF(0,3);
    const int oa4 = AOFF(1,0), oa5 = AOFF(1,1), oa6 = AOFF(1,2), oa7 = AOFF(1,3);
    const int ob0 = BOFF(0), ob1 = BOFF(1), ob2 = BOFF(2), ob3 = BOFF(3);

    f32x4 acc[8][4];
#pragma unroll
    for (int i = 0; i < 8; i++)
#pragma unroll
        for (int j = 0; j < 4; j++)
            acc[i][j] = (f32x4){0.f, 0.f, 0.f, 0.f};

    // ---- prologue: stage tiles 0,1,2; land tile 0; pre-read tile-0 cluster-1 frags
    STAGE_A(0) STAGE_B(0)
    STAGE_A(1) STAGE_B(1)
    STAGE_A(2) STAGE_B(2)
    asm volatile("s_waitcnt vmcnt(8)" ::: "memory");
    __builtin_amdgcn_s_barrier();

    bf16x8 aC0 = LD8(&Asm[0][0] + oa0);
    bf16x8 aC1 = LD8(&Asm[0][0] + oa1);
    bf16x8 aC2 = LD8(&Asm[0][0] + oa2);
    bf16x8 aC3 = LD8(&Asm[0][0] + oa3);
    bf16x8 bE0 = LD8(&Bsm[0][0] + ob0);
    bf16x8 bE1 = LD8(&Bsm[0][0] + ob1);
    bf16x8 bE2 = LD8(&Bsm[0][0] + ob2);
    bf16x8 bE3 = LD8(&Bsm[0][0] + ob3);
    bf16x8 aO0 = aC0, aO1 = aC1, aO2 = aC2, aO3 = aC3;   // defined init
    bf16x8 bO0 = bE0, bO1 = bE1, bO2 = bE2, bO3 = bE3;

    // ---- main loop: 2-tile unroll for E/O register parity
    for (int t = 0; t < 124; t += 2) {
        TILE(t,   aC0,aC1,aC2,aC3, bE0,bE1,bE2,bE3,
                  aO0,aO1,aO2,aO3, bO0,bO1,bO2,bO3, 1, "s_waitcnt vmcnt(8)", 1);
        TILE(t+1, aO0,aO1,aO2,aO3, bO0,bO1,bO2,bO3,
                  aC0,aC1,aC2,aC3, bE0,bE1,bE2,bE3, 1, "s_waitcnt vmcnt(8)", 1);
    }
    TILE(124, aC0,aC1,aC2,aC3, bE0,bE1,bE2,bE3,
              aO0,aO1,aO2,aO3, bO0,bO1,bO2,bO3, 1, "s_waitcnt vmcnt(8)", 1);
    TILE(125, aO0,aO1,aO2,aO3, bO0,bO1,bO2,bO3,
              aC0,aC1,aC2,aC3, bE0,bE1,bE2,bE3, 0, "s_waitcnt vmcnt(4)", 1);
    TILE(126, aC0,aC1,aC2,aC3, bE0,bE1,bE2,bE3,
              aO0,aO1,aO2,aO3, bO0,bO1,bO2,bO3, 0, "s_waitcnt vmcnt(0)", 1);
    TILE(127, aO0,aO1,aO2,aO3, bO0,bO1,bO2,bO3,
              aC0,aC1,aC2,aC3, bE0,bE1,bE2,bE3, 0, "s_nop 0",            0);

    // ---- epilogue: C/D layout col = lane&15, row = (lane>>4)*4 + r
    const int cc0 = bcol + wn * 64 + (lane & 15);
    const int rr0 = brow + wm * 128 + (lane >> 4) * 4;

    float bv[4];
#pragma unroll
    for (int ni = 0; ni < 4; ni++) bv[ni] = bias[cc0 + ni * 16];

#pragma unroll
    for (int p = 0; p < 2; p++) {
#pragma unroll
        for (int i = 0; i < 4; i++) {
#pragma unroll
            for (int r = 0; r < 4; r++) {
                const size_t row = (size_t)(rr0 + p * 64 + i * 16 + r);
#pragma unroll
                for (int ni = 0; ni < 4; ni++) {
                    C[row * N_DIM + cc0 + ni * 16] = acc[p * 4 + i][ni][r] + bv[ni];
                }
            }
        }
    }
}

// ---------------- safety-net fallback (no workspace): plain fp32 dot ----------------
__global__ void gemm_fallback_f32(const float* __restrict__ A, const float* __restrict__ B,
                                  const float* __restrict__ bias, float* __restrict__ C) {
    int n = blockIdx.x * 16 + threadIdx.x;
    int m = blockIdx.y * 16 + threadIdx.y;
    if (m >= M_DIM || n >= N_DIM) return;
    const float4* a = reinterpret_cast<const float4*>(A + (size_t)m * K_DIM);
    const float4* b = reinterpret_cast<const float4*>(B + (size_t)n * K_DIM);
    float s = 0.f;
    for (int k = 0; k < K_DIM / 4; k++) {
        float4 x = a[k], y = b[k];
        s += x.x * y.x + x.y * y.y + x.z * y.z + x.w * y.w;
    }
    C[(size_t)m * N_DIM + n] = s + bias[n];
}

extern "C" void kernel_launch(void* const* d_in, const int* in_sizes, int n_in,
                              void* d_out, int out_size, void* d_ws, size_t ws_size,
                              hipStream_t stream) {
    const float* x    = (const float*)d_in[0];   // [M][K] fp32
    const float* w    = (const float*)d_in[1];   // [N][K] fp32 (B^T layout)
    const float* bias = (const float*)d_in[2];   // [N] fp32
    float* out = (float*)d_out;

    const size_t xb = (size_t)M_DIM * K_DIM * sizeof(bf16_t);   // 64 MB
    const size_t wb = (size_t)N_DIM * K_DIM * sizeof(bf16_t);   // 32 MB

    if (ws_size >= xb + wb) {
        bf16_t* xbf = (bf16_t*)d_ws;
        bf16_t* wbf = (bf16_t*)((char*)d_ws + xb);

        cvt_f32_to_bf16<<<2048, 256, 0, stream>>>(x, xbf, (M_DIM * K_DIM) / 8);
        cvt_f32_to_bf16<<<1024, 256, 0, stream>>>(w, wbf, (N_DIM * K_DIM) / 8);

        const int grid = (M_DIM / BM) * (N_DIM / BN);   // 32 * 16 = 512
        gemm_bf16_sgb<<<grid, 512, 0, stream>>>(xbf, wbf, bias, out);
    } else {
        dim3 block(16, 16);
        dim3 grid(N_DIM / 16, M_DIM / 16);
        gemm_fallback_f32<<<grid, block, 0, stream>>>(x, w, bias, out);
    }
}